// Round 1
// baseline (205.870 us; speedup 1.0000x reference)
//
#include <hip/hip_runtime.h>
#include <hip/hip_bf16.h>
#include <stdint.h>

// Problem constants: fm_t is (1024, 64, 16, 16) fp32 -> X is [N=1024, D=16384].
// loss = mean_{i,j} ((sq_i + sq_j - 2*g_ij)/D)^2,  g = X X^T, sq_i = |x_i|^2.
#define N_ROWS 1024
#define KDIM   16384

typedef __attribute__((ext_vector_type(8))) __bf16 bf16x8;
typedef __attribute__((ext_vector_type(4))) float  f32x4;

#define GLOBAL_AS __attribute__((address_space(1)))
#define LDS_AS    __attribute__((address_space(3)))

__device__ __forceinline__ unsigned short f32_to_bf16_rne(float f) {
    unsigned int u = __float_as_uint(f);
    unsigned int lsb = (u >> 16) & 1u;
    u += 0x7fffu + lsb;
    return (unsigned short)(u >> 16);
}

// Kernel 1: fused fp32->bf16 cast of X plus exact fp32 row norms sq[i].
// One block per row: 16384 floats = 4096 float4 = 16 float4/thread.
__global__ __launch_bounds__(256) void cast_sq_kernel(
        const float* __restrict__ X, unsigned short* __restrict__ Xb,
        float* __restrict__ sq) {
    const int row = blockIdx.x;
    const float4* src = (const float4*)(X + (size_t)row * KDIM);
    uint2* dst = (uint2*)(Xb + (size_t)row * KDIM);
    float ss = 0.f;
#pragma unroll
    for (int c = 0; c < 16; ++c) {
        int idx = c * 256 + threadIdx.x;
        float4 v = src[idx];
        ss += v.x * v.x + v.y * v.y + v.z * v.z + v.w * v.w;
        uint2 p;
        p.x = (unsigned int)f32_to_bf16_rne(v.x) | ((unsigned int)f32_to_bf16_rne(v.y) << 16);
        p.y = (unsigned int)f32_to_bf16_rne(v.z) | ((unsigned int)f32_to_bf16_rne(v.w) << 16);
        dst[idx] = p;
    }
#pragma unroll
    for (int o = 32; o; o >>= 1) ss += __shfl_down(ss, o, 64);
    __shared__ float red[4];
    int lane = threadIdx.x & 63, wv = threadIdx.x >> 6;
    if (lane == 0) red[wv] = ss;
    __syncthreads();
    if (threadIdx.x == 0) sq[row] = red[0] + red[1] + red[2] + red[3];
}

// Kernel 2: split-K bf16 Gram GEMM (NT: both operands are rows of X).
// BM=BN=128, BK=64, 256 threads = 2x2 waves, each wave 64x64 via 4x4
// mfma_f32_16x16x32_bf16 frags. global_load_lds width-16 staging (m97 shape).
// Partial tiles accumulated into G via fp32 atomicAdd (KS=8 contenders/elem).
__global__ __launch_bounds__(256) void gram_gemm_kernel(
        const unsigned short* __restrict__ Xb, float* __restrict__ G) {
    __shared__ unsigned short As[128 * 64];  // 16 KB, row-major [r][k]
    __shared__ unsigned short Bs[128 * 64];  // 16 KB

    const int row0 = blockIdx.x * 128;
    const int col0 = blockIdx.y * 128;
    const int kbeg = blockIdx.z * (KDIM / 8);   // split-K = 8 -> 2048 per block
    const int kend = kbeg + (KDIM / 8);

    const int tid  = threadIdx.x;
    const int lane = tid & 63;
    const int wv   = tid >> 6;
    const int wm   = (wv >> 1) * 64;   // wave row offset in tile
    const int wn   = (wv & 1) * 64;    // wave col offset in tile
    const int lr   = lane & 15;        // m (A) / n (B) within 16
    const int lk   = (lane >> 4) * 8;  // k sub-offset

    f32x4 acc[4][4] = {};

    for (int k0 = kbeg; k0 < kend; k0 += 64) {
        // ---- stage A and B tiles: 1024 chunks of 16B each, 4 per thread ----
#pragma unroll
        for (int it = 0; it < 4; ++it) {
            int c  = it * 256 + tid;      // 0..1023 linear chunk id
            int r  = c >> 3;              // row in tile 0..127
            int kc = (c & 7) << 3;        // k elem offset 0..56
            const unsigned short* ga = Xb + (size_t)(row0 + r) * KDIM + k0 + kc;
            const unsigned short* gb = Xb + (size_t)(col0 + r) * KDIM + k0 + kc;
            __builtin_amdgcn_global_load_lds((GLOBAL_AS void*)(void*)ga,
                                             (LDS_AS void*)&As[c * 8], 16, 0, 0);
            __builtin_amdgcn_global_load_lds((GLOBAL_AS void*)(void*)gb,
                                             (LDS_AS void*)&Bs[c * 8], 16, 0, 0);
        }
        __syncthreads();  // drains vmcnt for global_load_lds

        // ---- compute: 2 k-steps of 32, 16 MFMA each ----
#pragma unroll
        for (int s = 0; s < 2; ++s) {
            const int ko = s * 32 + lk;
            bf16x8 af[4], bfq[4];
#pragma unroll
            for (int i = 0; i < 4; ++i)
                af[i] = *(const bf16x8*)&As[(wm + i * 16 + lr) * 64 + ko];
#pragma unroll
            for (int j = 0; j < 4; ++j)
                bfq[j] = *(const bf16x8*)&Bs[(wn + j * 16 + lr) * 64 + ko];
#pragma unroll
            for (int i = 0; i < 4; ++i)
#pragma unroll
                for (int j = 0; j < 4; ++j)
                    acc[i][j] = __builtin_amdgcn_mfma_f32_16x16x32_bf16(
                        af[i], bfq[j], acc[i][j], 0, 0, 0);
        }
        __syncthreads();
    }

    // ---- epilogue: C/D layout col=lane&15, row=(lane>>4)*4+reg ----
    const int crow0 = row0 + wm + (lane >> 4) * 4;
    const int ccol0 = col0 + wn + (lane & 15);
#pragma unroll
    for (int i = 0; i < 4; ++i)
#pragma unroll
        for (int j = 0; j < 4; ++j)
#pragma unroll
            for (int r = 0; r < 4; ++r) {
                int grow = crow0 + i * 16 + r;
                int gcol = ccol0 + j * 16;
                atomicAdd(&G[(size_t)grow * N_ROWS + gcol], acc[i][j][r]);
            }
}

// Kernel 3: loss = mean_{i,j} ((sq_i + sq_j - 2*g_ij)/D)^2
__global__ __launch_bounds__(256) void loss_kernel(
        const float* __restrict__ G, const float* __restrict__ sq,
        float* __restrict__ out) {
    const float invD = 1.0f / (float)KDIM;
    float acc = 0.f;
    for (int idx = blockIdx.x * 256 + threadIdx.x; idx < N_ROWS * N_ROWS;
         idx += gridDim.x * 256) {
        int i = idx >> 10;
        int j = idx & (N_ROWS - 1);
        float v = (sq[i] + sq[j] - 2.0f * G[idx]) * invD;
        acc += v * v;
    }
#pragma unroll
    for (int o = 32; o; o >>= 1) acc += __shfl_down(acc, o, 64);
    __shared__ float red[4];
    int lane = threadIdx.x & 63, wv = threadIdx.x >> 6;
    if (lane == 0) red[wv] = acc;
    __syncthreads();
    if (threadIdx.x == 0) {
        float total = red[0] + red[1] + red[2] + red[3];
        atomicAdd(out, total * (1.0f / ((float)N_ROWS * (float)N_ROWS)));
    }
}

extern "C" void kernel_launch(void* const* d_in, const int* in_sizes, int n_in,
                              void* d_out, int out_size, void* d_ws, size_t ws_size,
                              hipStream_t stream) {
    // d_in[0] = fm_s (unused per reference bug), d_in[1] = fm_t
    const float* fm_t = (const float*)d_in[1];
    float* out = (float*)d_out;

    // Workspace layout: Xb bf16 [32 MB] | sq fp32 [4 KB] | G fp32 [4 MB]
    char* ws = (char*)d_ws;
    unsigned short* Xb = (unsigned short*)ws;
    float* sq = (float*)(ws + (size_t)N_ROWS * KDIM * 2);
    float* G  = (float*)(ws + (size_t)N_ROWS * KDIM * 2 + 4096);

    hipMemsetAsync(G, 0, (size_t)N_ROWS * N_ROWS * sizeof(float), stream);
    hipMemsetAsync(out, 0, sizeof(float), stream);

    cast_sq_kernel<<<dim3(N_ROWS), 256, 0, stream>>>(fm_t, Xb, sq);
    gram_gemm_kernel<<<dim3(8, 8, 8), 256, 0, stream>>>(Xb, G);
    loss_kernel<<<dim3(256), 256, 0, stream>>>(G, sq, out);
}